// Round 1
// baseline (102.225 us; speedup 1.0000x reference)
//
#include <hip/hip_runtime.h>

#define Bb 16
#define Ss 2048
#define Dd 128

typedef __attribute__((ext_vector_type(4))) float f32x4;
typedef __attribute__((ext_vector_type(4))) short s16x4;

__device__ __forceinline__ unsigned short f2bf(float f) {
  union { float f; unsigned u; } v; v.f = f;
  unsigned r = v.u + 0x7fffu + ((v.u >> 16) & 1u);   // round-to-nearest-even
  return (unsigned short)(r >> 16);
}

__global__ __launch_bounds__(256, 2)
void attn_kernel(const float* __restrict__ Q, const float* __restrict__ K,
                 const float* __restrict__ V, float* __restrict__ O) {
  constexpr int LDK = 136;   // Kt row stride in bf16 elems (128 + 8 pad: bank-spread)
  constexpr int LDV = 68;    // Vt row stride in bf16 elems (64 + 4 pad)
  __shared__ unsigned short Kt[64 * LDK];    // K tile, row-major [kv][d]
  __shared__ unsigned short Vt[128 * LDV];   // V tile, TRANSPOSED [d][kv]

  const int tid = threadIdx.x;
  const int l   = tid & 63;
  const int w   = tid >> 6;     // wave 0..3
  const int ql  = l & 15;
  const int hi  = l >> 4;       // 0..3

  // XCD-chunked swizzle: 512 blocks, 8 XCDs -> 64 consecutive per XCD (bijective)
  const int idx = blockIdx.x;
  const int swz = (idx & 7) * 64 + (idx >> 3);
  const int b   = swz >> 5;     // batch 0..15
  const int qt  = swz & 31;     // q-tile 0..31
  const int q0  = qt * 64 + w * 16;

  const float* Qb = Q + ((size_t)b * Ss + q0) * Dd;
  const float* Kb = K + (size_t)b * Ss * Dd;
  const float* Vb = V + (size_t)b * Ss * Dd;
  float*       Ob = O + ((size_t)b * Ss + q0) * Dd;

  // Q fragments (B operand of swapped QK^T): qf[dq][j] = Q[q0+ql][dq*16 + hi*4 + j]
  s16x4 qf[8];
  #pragma unroll
  for (int dq = 0; dq < 8; ++dq) {
    f32x4 f = *(const f32x4*)(Qb + ql * Dd + dq * 16 + hi * 4);
    s16x4 s;
    s[0] = (short)f2bf(f[0]); s[1] = (short)f2bf(f[1]);
    s[2] = (short)f2bf(f[2]); s[3] = (short)f2bf(f[3]);
    qf[dq] = s;
  }

  const f32x4 vzero = {0.f, 0.f, 0.f, 0.f};
  f32x4 acc[8];
  #pragma unroll
  for (int i = 0; i < 8; ++i) acc[i] = vzero;
  float m2   = -__builtin_inff();      // running max in log2 domain
  float lsum = 0.f;                    // running denominator
  constexpr float Cs = 1.44269504088896340736f / 11.31370849898476039041f; // log2(e)/sqrt(128)

  for (int kv0 = 0; kv0 < Ss; kv0 += 64) {
    __syncthreads();   // previous tile's reads done before overwrite

    // ---- stage K tile: 64x128 fp32 -> bf16 Kt[kv][d] ----
    #pragma unroll
    for (int i = 0; i < 8; ++i) {
      int u  = i * 256 + tid;
      int kv = u >> 5;
      int d0 = (u & 31) * 4;
      f32x4 f = *(const f32x4*)(Kb + (size_t)(kv0 + kv) * Dd + d0);
      s16x4 s;
      s[0] = (short)f2bf(f[0]); s[1] = (short)f2bf(f[1]);
      s[2] = (short)f2bf(f[2]); s[3] = (short)f2bf(f[3]);
      *(s16x4*)&Kt[kv * LDK + d0] = s;
    }
    // ---- stage V tile transposed: Vt[d][kv] (coalesced global, b64 LDS writes) ----
    {
      int d  = tid & 127;
      int ab = tid >> 7;   // 0..1
      #pragma unroll
      for (int i = 0; i < 8; ++i) {
        int a = i * 2 + ab;   // kv group: rows 4a..4a+3
        const float* vp = Vb + (size_t)(kv0 + a * 4) * Dd + d;
        float f0 = vp[0];
        float f1 = vp[Dd];
        float f2 = vp[2 * Dd];
        float f3 = vp[3 * Dd];
        s16x4 s;
        s[0] = (short)f2bf(f0); s[1] = (short)f2bf(f1);
        s[2] = (short)f2bf(f2); s[3] = (short)f2bf(f3);
        *(s16x4*)&Vt[d * LDV + a * 4] = s;
      }
    }
    __syncthreads();

    // ---- S^T = K · Q^T (swapped: lane's column = its q row) ----
    float p[16];
    #pragma unroll
    for (int kk = 0; kk < 4; ++kk) {
      f32x4 s = vzero;
      #pragma unroll
      for (int dq = 0; dq < 8; ++dq) {
        s16x4 a = *(const s16x4*)&Kt[(kk * 16 + ql) * LDK + dq * 16 + hi * 4];
        s = __builtin_amdgcn_mfma_f32_16x16x16bf16_1k(a, qf[dq], s, 0, 0, 0);
      }
      #pragma unroll
      for (int r = 0; r < 4; ++r) p[kk * 4 + r] = s[r];
    }

    // ---- online softmax; lane's 16 p-values all belong to q = q0+ql ----
    float tmax = p[0];
    #pragma unroll
    for (int i = 1; i < 16; ++i) tmax = fmaxf(tmax, p[i]);
    tmax = fmaxf(tmax, __shfl_xor(tmax, 16));
    tmax = fmaxf(tmax, __shfl_xor(tmax, 32));
    float m2n   = fmaxf(m2, tmax * Cs);
    float alpha = __builtin_amdgcn_exp2f(m2 - m2n);   // first iter: exp2(-inf)=0
    float rsum  = 0.f;
    #pragma unroll
    for (int i = 0; i < 16; ++i) {
      p[i] = __builtin_amdgcn_exp2f(fmaf(p[i], Cs, -m2n));
      rsum += p[i];
    }
    rsum += __shfl_xor(rsum, 16);
    rsum += __shfl_xor(rsum, 32);
    lsum = lsum * alpha + rsum;
    m2   = m2n;

    // rescale accumulator: acc rows are q_local = 4*hi + r -> gather alpha per row
    f32x4 av;
    #pragma unroll
    for (int r = 0; r < 4; ++r) av[r] = __shfl(alpha, hi * 4 + r);
    #pragma unroll
    for (int dt = 0; dt < 8; ++dt) acc[dt] *= av;

    // P -> bf16 A-fragments: C-layout row (4*hi+r) IS the 16x16x16 A k-index
    s16x4 pa[4];
    #pragma unroll
    for (int kk = 0; kk < 4; ++kk) {
      s16x4 s;
      s[0] = (short)f2bf(p[kk * 4 + 0]);
      s[1] = (short)f2bf(p[kk * 4 + 1]);
      s[2] = (short)f2bf(p[kk * 4 + 2]);
      s[3] = (short)f2bf(p[kk * 4 + 3]);
      pa[kk] = s;
    }

    // ---- O += P · V ----
    #pragma unroll
    for (int kk = 0; kk < 4; ++kk) {
      #pragma unroll
      for (int dt = 0; dt < 8; ++dt) {
        s16x4 bv = *(const s16x4*)&Vt[(dt * 16 + ql) * LDV + kk * 16 + hi * 4];
        acc[dt] = __builtin_amdgcn_mfma_f32_16x16x16bf16_1k(pa[kk], bv, acc[dt], 0, 0, 0);
      }
    }
  }

  // ---- epilogue: divide by running sum (gathered per acc row), fp32 store ----
  float inv[4];
  #pragma unroll
  for (int r = 0; r < 4; ++r) inv[r] = 1.f / __shfl(lsum, hi * 4 + r);
  #pragma unroll
  for (int dt = 0; dt < 8; ++dt) {
    #pragma unroll
    for (int r = 0; r < 4; ++r) {
      Ob[(size_t)(hi * 4 + r) * Dd + dt * 16 + ql] = acc[dt][r] * inv[r];
    }
  }
}

extern "C" void kernel_launch(void* const* d_in, const int* in_sizes, int n_in,
                              void* d_out, int out_size, void* d_ws, size_t ws_size,
                              hipStream_t stream) {
  const float* Q = (const float*)d_in[0];
  const float* K = (const float*)d_in[1];
  const float* V = (const float*)d_in[2];
  float* O = (float*)d_out;
  attn_kernel<<<dim3(Bb * (Ss / 64)), dim3(256), 0, stream>>>(Q, K, V, O);
}

// Round 2
// 77.592 us; speedup vs baseline: 1.3175x; 1.3175x over previous
//
#include <hip/hip_runtime.h>

#define Bb 16
#define Ss 2048
#define Dd 128

typedef __attribute__((ext_vector_type(4))) float f32x4;
typedef __attribute__((ext_vector_type(4))) short s16x4;
typedef __attribute__((ext_vector_type(8))) short s16x8;
typedef __attribute__((ext_vector_type(4))) __bf16 bf16x4;

__device__ __forceinline__ s16x4 cvt4(f32x4 f) {
  union { bf16x4 h; s16x4 s; } u;
  u.h = __builtin_convertvector(f, bf16x4);   // compiler emits v_cvt_pk_bf16_f32
  return u.s;
}

__global__ __launch_bounds__(256, 2)
void attn_kernel(const float* __restrict__ Q, const float* __restrict__ K,
                 const float* __restrict__ V, float* __restrict__ O) {
  constexpr int LDK = 136;   // Kt row stride (bf16 elems), pad kills D=128 bank alias
  constexpr int LDV = 68;    // Vt row stride (bf16 elems)
  constexpr int NT  = Ss / 64;
  __shared__ unsigned short Kt[64 * LDK];    // K tile [kv][d]
  __shared__ unsigned short Vt[128 * LDV];   // V tile transposed [d][kv]

  const int tid = threadIdx.x;
  const int l   = tid & 63;
  const int w   = tid >> 6;
  const int ql  = l & 15;
  const int hi  = l >> 4;

  // XCD-chunked bijective swizzle (512 blocks, 8 XCDs)
  const int idx = blockIdx.x;
  const int swz = (idx & 7) * 64 + (idx >> 3);
  const int b   = swz >> 5;
  const int qt  = swz & 31;
  const int q0  = qt * 64 + w * 16;

  const float* Qb = Q + ((size_t)b * Ss + q0) * Dd;
  const float* Kb = K + (size_t)b * Ss * Dd;
  const float* Vb = V + (size_t)b * Ss * Dd;
  float*       Ob = O + ((size_t)b * Ss + q0) * Dd;

  // Q fragments (B-operand of swapped QK^T, 16x16x32): qf[dq][j] = Q[q0+ql][dq*32+hi*8+j]
  s16x8 qf[4];
  #pragma unroll
  for (int dq = 0; dq < 4; ++dq) {
    f32x4 fa = *(const f32x4*)(Qb + ql * Dd + dq * 32 + hi * 8);
    f32x4 fb = *(const f32x4*)(Qb + ql * Dd + dq * 32 + hi * 8 + 4);
    union { s16x8 v; s16x4 h[2]; } u;
    u.h[0] = cvt4(fa); u.h[1] = cvt4(fb);
    qf[dq] = u.v;
  }

  const f32x4 vzero = {0.f, 0.f, 0.f, 0.f};
  f32x4 acc[8];
  #pragma unroll
  for (int i = 0; i < 8; ++i) acc[i] = vzero;
  float m2   = -__builtin_inff();      // running max, log2 domain
  float lsum = 0.f;
  constexpr float Cs  = 1.44269504088896340736f / 11.31370849898476039041f; // log2e/sqrt(128)
  constexpr float THR = 10.0f;         // defer-max threshold (log2 domain)

  const int dV  = tid & 127;           // V staging: this thread's column
  const int abV = tid >> 7;

  // ---- register staging buffers (T14: issue loads a tile ahead) ----
  f32x4 kreg[8];
  f32x4 vreg[8];
  {
    #pragma unroll
    for (int i = 0; i < 8; ++i) {
      int u = i * 256 + tid;
      kreg[i] = *(const f32x4*)(Kb + (size_t)(u >> 5) * Dd + (u & 31) * 4);
    }
    const float* Vp = Vb + dV;
    #pragma unroll
    for (int i = 0; i < 8; ++i) {
      int a = i * 2 + abV;
      const float* vp = Vp + (size_t)(a * 4) * Dd;
      f32x4 t; t[0] = vp[0]; t[1] = vp[Dd]; t[2] = vp[2 * Dd]; t[3] = vp[3 * Dd];
      vreg[i] = t;
    }
  }

  for (int t = 0; t < NT; ++t) {
    __syncthreads();   // previous tile's LDS reads complete

    // ---- write staged regs -> LDS (cvt_pk) ----
    #pragma unroll
    for (int i = 0; i < 8; ++i) {
      int u = i * 256 + tid;
      *(s16x4*)&Kt[(u >> 5) * LDK + (u & 31) * 4] = cvt4(kreg[i]);
    }
    #pragma unroll
    for (int i = 0; i < 8; ++i) {
      int a = i * 2 + abV;
      *(s16x4*)&Vt[dV * LDV + a * 4] = cvt4(vreg[i]);
    }
    __syncthreads();

    // ---- issue next tile's global loads (latency hides under compute) ----
    if (t + 1 < NT) {
      const float* Kp = Kb + (size_t)(t + 1) * 64 * Dd;
      #pragma unroll
      for (int i = 0; i < 8; ++i) {
        int u = i * 256 + tid;
        kreg[i] = *(const f32x4*)(Kp + (size_t)(u >> 5) * Dd + (u & 31) * 4);
      }
      const float* Vp = Vb + (size_t)(t + 1) * 64 * Dd + dV;
      #pragma unroll
      for (int i = 0; i < 8; ++i) {
        int a = i * 2 + abV;
        const float* vp = Vp + (size_t)(a * 4) * Dd;
        f32x4 tt; tt[0] = vp[0]; tt[1] = vp[Dd]; tt[2] = vp[2 * Dd]; tt[3] = vp[3 * Dd];
        vreg[i] = tt;
      }
    }

    // ---- S^T = K · Q^T via 16x16x32 MFMA ----
    f32x4 p4[4];
    __builtin_amdgcn_s_setprio(1);
    #pragma unroll
    for (int kk = 0; kk < 4; ++kk) {
      f32x4 s = vzero;
      #pragma unroll
      for (int dq = 0; dq < 4; ++dq) {
        s16x8 afr = *(const s16x8*)&Kt[(kk * 16 + ql) * LDK + dq * 32 + hi * 8];
        s = __builtin_amdgcn_mfma_f32_16x16x32_bf16(afr, qf[dq], s, 0, 0, 0);
      }
      p4[kk] = s;
    }
    __builtin_amdgcn_s_setprio(0);

    // ---- online softmax (lane-local q row) with defer-max ----
    float tmax = p4[0][0];
    #pragma unroll
    for (int kk = 0; kk < 4; ++kk)
      #pragma unroll
      for (int r = 0; r < 4; ++r) tmax = fmaxf(tmax, p4[kk][r]);
    tmax = fmaxf(tmax, __shfl_xor(tmax, 16));
    tmax = fmaxf(tmax, __shfl_xor(tmax, 32));
    float mt = tmax * Cs;
    if (__any(mt > m2 + THR)) {        // first tile: m2=-inf -> taken
      float m2n   = fmaxf(m2, mt);
      float alpha = __builtin_amdgcn_exp2f(m2 - m2n);
      f32x4 av;
      #pragma unroll
      for (int r = 0; r < 4; ++r) av[r] = __shfl(alpha, hi * 4 + r);
      #pragma unroll
      for (int dt = 0; dt < 8; ++dt) acc[dt] *= av;
      lsum *= alpha;
      m2 = m2n;
    }
    float rsum = 0.f;
    #pragma unroll
    for (int kk = 0; kk < 4; ++kk)
      #pragma unroll
      for (int r = 0; r < 4; ++r) {
        float e = __builtin_amdgcn_exp2f(fmaf(p4[kk][r], Cs, -m2));
        p4[kk][r] = e;
        rsum += e;
      }
    rsum += __shfl_xor(rsum, 16);
    rsum += __shfl_xor(rsum, 32);
    lsum += rsum;

    // P -> bf16 A-fragments: S^T C-row (4*hi+r) IS the 16x16x16 A k-index
    s16x4 pa[4];
    #pragma unroll
    for (int kk = 0; kk < 4; ++kk) pa[kk] = cvt4(p4[kk]);

    // ---- O += P · V (16x16x16, Vt b64 B-fragments) ----
    __builtin_amdgcn_s_setprio(1);
    #pragma unroll
    for (int kk = 0; kk < 4; ++kk) {
      #pragma unroll
      for (int dt = 0; dt < 8; ++dt) {
        s16x4 bv = *(const s16x4*)&Vt[(dt * 16 + ql) * LDV + kk * 16 + hi * 4];
        acc[dt] = __builtin_amdgcn_mfma_f32_16x16x16bf16_1k(pa[kk], bv, acc[dt], 0, 0, 0);
      }
    }
    __builtin_amdgcn_s_setprio(0);
  }

  // ---- epilogue ----
  float inv[4];
  #pragma unroll
  for (int r = 0; r < 4; ++r) inv[r] = 1.f / __shfl(lsum, hi * 4 + r);
  #pragma unroll
  for (int dt = 0; dt < 8; ++dt) {
    #pragma unroll
    for (int r = 0; r < 4; ++r) {
      Ob[(size_t)(hi * 4 + r) * Dd + dt * 16 + ql] = acc[dt][r] * inv[r];
    }
  }
}

extern "C" void kernel_launch(void* const* d_in, const int* in_sizes, int n_in,
                              void* d_out, int out_size, void* d_ws, size_t ws_size,
                              hipStream_t stream) {
  const float* Q = (const float*)d_in[0];
  const float* K = (const float*)d_in[1];
  const float* V = (const float*)d_in[2];
  float* O = (float*)d_out;
  attn_kernel<<<dim3(Bb * (Ss / 64)), dim3(256), 0, stream>>>(Q, K, V, O);
}

// Round 3
// 74.282 us; speedup vs baseline: 1.3762x; 1.0446x over previous
//
#include <hip/hip_runtime.h>

#define Bb 16
#define Ss 2048
#define Dd 128

typedef __attribute__((ext_vector_type(4))) float f32x4;
typedef __attribute__((ext_vector_type(4))) short s16x4;
typedef __attribute__((ext_vector_type(8))) short s16x8;
typedef __attribute__((ext_vector_type(4))) __bf16 bf16x4;

__device__ __forceinline__ s16x4 cvt4(f32x4 f) {
  union { bf16x4 h; s16x4 s; } u;
  u.h = __builtin_convertvector(f, bf16x4);   // v_cvt_pk_bf16_f32 pairs
  return u.s;
}

__global__ __launch_bounds__(256, 2)
void attn_kernel(const float* __restrict__ Q, const float* __restrict__ K,
                 const float* __restrict__ V, float* __restrict__ O) {
  constexpr int LDK = 136;   // Kt row stride (bf16), 272B rows: 16B-aligned, bank-spread
  constexpr int LDV = 72;    // Vs row stride (bf16), 144B rows: 16B-aligned
  constexpr int NT  = Ss / 64;
  __shared__ unsigned short Kt[2][64 * LDK];    // K tile [kv][d], double-buffered
  __shared__ unsigned short Vs[2][128 * LDV];   // V transposed+slot-permuted [d][slot]

  const int tid = threadIdx.x;
  const int l   = tid & 63;
  const int w   = tid >> 6;
  const int ql  = l & 15;
  const int hi  = l >> 4;

  // XCD-chunked bijective swizzle (512 blocks, 8 XCDs)
  const int idx = blockIdx.x;
  const int swz = (idx & 7) * 64 + (idx >> 3);
  const int b   = swz >> 5;
  const int qt  = swz & 31;
  const int q0  = qt * 64 + w * 16;

  const float* Qb = Q + ((size_t)b * Ss + q0) * Dd;
  const float* Kb = K + (size_t)b * Ss * Dd;
  const float* Vb = V + (size_t)b * Ss * Dd;
  float*       Ob = O + ((size_t)b * Ss + q0) * Dd;

  // Q fragments (B-operand of swapped QK^T): qf[dq][j] = Q[q0+ql][dq*32+hi*8+j]
  s16x8 qf[4];
  #pragma unroll
  for (int dq = 0; dq < 4; ++dq) {
    f32x4 fa = *(const f32x4*)(Qb + ql * Dd + dq * 32 + hi * 8);
    f32x4 fb = *(const f32x4*)(Qb + ql * Dd + dq * 32 + hi * 8 + 4);
    union { s16x8 v; s16x4 h[2]; } u;
    u.h[0] = cvt4(fa); u.h[1] = cvt4(fb);
    qf[dq] = u.v;
  }

  const f32x4 vzero = {0.f, 0.f, 0.f, 0.f};
  f32x4 acc[8];
  #pragma unroll
  for (int i = 0; i < 8; ++i) acc[i] = vzero;
  float m2   = -__builtin_inff();
  float lsum = 0.f;
  constexpr float Cs  = 1.44269504088896340736f / 11.31370849898476039041f; // log2e/sqrt(128)
  constexpr float THR = 10.0f;

  const int dV  = tid & 127;     // V staging column (d)
  const int abV = tid >> 7;

  f32x4 kreg[8];
  f32x4 vreg[8];

  // ---- staging helpers ----
  auto load_tile = [&](int t) {
    const float* Kp = Kb + (size_t)t * 64 * Dd;
    #pragma unroll
    for (int i = 0; i < 8; ++i) {
      int u = i * 256 + tid;
      kreg[i] = *(const f32x4*)(Kp + (size_t)(u >> 5) * Dd + (u & 31) * 4);
    }
    const float* Vp = Vb + (size_t)t * 64 * Dd + dV;
    #pragma unroll
    for (int i = 0; i < 8; ++i) {
      int a = i * 2 + abV;
      const float* vp = Vp + (size_t)(a * 4) * Dd;
      f32x4 tt; tt[0] = vp[0]; tt[1] = vp[Dd]; tt[2] = vp[2 * Dd]; tt[3] = vp[3 * Dd];
      vreg[i] = tt;
    }
  };
  auto write_tile = [&](int c) {
    #pragma unroll
    for (int i = 0; i < 8; ++i) {
      int u = i * 256 + tid;
      *(s16x4*)&Kt[c][(u >> 5) * LDK + (u & 31) * 4] = cvt4(kreg[i]);
    }
    #pragma unroll
    for (int i = 0; i < 8; ++i) {
      int a = i * 2 + abV;
      // slot-permute: rows kv=4a..4a+3 -> slots base 32*(a>>3)+8*(a&3)+4*((a>>2)&1)
      int sb = 32 * (a >> 3) + 8 * (a & 3) + 4 * ((a >> 2) & 1);
      *(s16x4*)&Vs[c][dV * LDV + sb] = cvt4(vreg[i]);
    }
  };

  // ---- prologue: tile0 -> buf0; tile1 -> regs ----
  load_tile(0);
  write_tile(0);
  load_tile(1);
  __syncthreads();

  for (int t = 0; t < NT; ++t) {
    const int c = t & 1;

    // ---- S^T = K · Q^T (16x16x32) ----
    f32x4 p4[4];
    __builtin_amdgcn_s_setprio(1);
    #pragma unroll
    for (int kk = 0; kk < 4; ++kk) {
      f32x4 s = vzero;
      #pragma unroll
      for (int dq = 0; dq < 4; ++dq) {
        s16x8 afr = *(const s16x8*)&Kt[c][(kk * 16 + ql) * LDK + dq * 32 + hi * 8];
        s = __builtin_amdgcn_mfma_f32_16x16x32_bf16(afr, qf[dq], s, 0, 0, 0);
      }
      p4[kk] = s;
    }
    __builtin_amdgcn_s_setprio(0);

    // ---- online softmax (lane-local q row) with defer-max ----
    float tmax = p4[0][0];
    #pragma unroll
    for (int kk = 0; kk < 4; ++kk)
      #pragma unroll
      for (int r = 0; r < 4; ++r) tmax = fmaxf(tmax, p4[kk][r]);
    tmax = fmaxf(tmax, __shfl_xor(tmax, 16));
    tmax = fmaxf(tmax, __shfl_xor(tmax, 32));
    float mt = tmax * Cs;
    if (__any(mt > m2 + THR)) {
      float m2n   = fmaxf(m2, mt);
      float alpha = __builtin_amdgcn_exp2f(m2 - m2n);
      f32x4 av;
      #pragma unroll
      for (int r = 0; r < 4; ++r) av[r] = __shfl(alpha, hi * 4 + r);
      #pragma unroll
      for (int dt = 0; dt < 8; ++dt) acc[dt] *= av;
      lsum *= alpha;
      m2 = m2n;
    }
    float rsum = 0.f;
    #pragma unroll
    for (int kk = 0; kk < 4; ++kk)
      #pragma unroll
      for (int r = 0; r < 4; ++r) {
        float e = __builtin_amdgcn_exp2f(fmaf(p4[kk][r], Cs, -m2));
        p4[kk][r] = e;
        rsum += e;
      }
    rsum += __shfl_xor(rsum, 16);
    rsum += __shfl_xor(rsum, 32);
    lsum += rsum;

    // ---- overlap: write tile t+1 into buf^1; then issue loads for t+2 ----
    if (t + 1 < NT) write_tile(c ^ 1);
    if (t + 2 < NT) load_tile(t + 2);

    // P -> bf16 fragments; S^T C-row (4hi+r) is the A k-index, slot-permuted
    s16x4 pa[4];
    #pragma unroll
    for (int kk = 0; kk < 4; ++kk) pa[kk] = cvt4(p4[kk]);

    // ---- O += P · V (16x16x32, slot-permuted Vs, b128 B-fragments) ----
    __builtin_amdgcn_s_setprio(1);
    #pragma unroll
    for (int pvb = 0; pvb < 2; ++pvb) {
      union { s16x8 v; s16x4 h[2]; } ua;
      ua.h[0] = pa[pvb * 2]; ua.h[1] = pa[pvb * 2 + 1];
      #pragma unroll
      for (int dt = 0; dt < 8; ++dt) {
        s16x8 bv = *(const s16x8*)&Vs[c][(dt * 16 + ql) * LDV + pvb * 32 + hi * 8];
        acc[dt] = __builtin_amdgcn_mfma_f32_16x16x32_bf16(ua.v, bv, acc[dt], 0, 0, 0);
      }
    }
    __builtin_amdgcn_s_setprio(0);

    __syncthreads();   // buf[c] reads done; buf[c^1] writes visible
  }

  // ---- epilogue ----
  float inv[4];
  #pragma unroll
  for (int r = 0; r < 4; ++r) inv[r] = 1.f / __shfl(lsum, hi * 4 + r);
  #pragma unroll
  for (int dt = 0; dt < 8; ++dt) {
    #pragma unroll
    for (int r = 0; r < 4; ++r) {
      Ob[(size_t)(hi * 4 + r) * Dd + dt * 16 + ql] = acc[dt][r] * inv[r];
    }
  }
}

extern "C" void kernel_launch(void* const* d_in, const int* in_sizes, int n_in,
                              void* d_out, int out_size, void* d_ws, size_t ws_size,
                              hipStream_t stream) {
  const float* Q = (const float*)d_in[0];
  const float* K = (const float*)d_in[1];
  const float* V = (const float*)d_in[2];
  float* O = (float*)d_out;
  attn_kernel<<<dim3(Bb * (Ss / 64)), dim3(256), 0, stream>>>(Q, K, V, O);
}

// Round 4
// 67.388 us; speedup vs baseline: 1.5170x; 1.1023x over previous
//
#include <hip/hip_runtime.h>

#define Bb 16
#define Ss 2048
#define Dd 128

typedef __attribute__((ext_vector_type(4))) float f32x4;
typedef __attribute__((ext_vector_type(4))) short s16x4;
typedef __attribute__((ext_vector_type(8))) short s16x8;
typedef __attribute__((ext_vector_type(4))) __bf16 bf16x4;

__device__ __forceinline__ s16x4 cvt4(f32x4 f) {
  union { bf16x4 h; s16x4 s; } u;
  u.h = __builtin_convertvector(f, bf16x4);   // v_cvt_pk_bf16_f32 pairs
  return u.s;
}

__global__ __launch_bounds__(512, 4)
void attn_kernel(const float* __restrict__ Q, const float* __restrict__ K,
                 const float* __restrict__ V, float* __restrict__ O) {
  constexpr int LDK = 136;   // Kt row stride (bf16): 272B rows, 4-way-max patterns
  constexpr int LDV = 68;    // Vt row stride (bf16): 136B rows, 4-way write/read
  constexpr int NT  = Ss / 64;
  __shared__ unsigned short Kt[2][64 * LDK];    // K tile [kv][d]
  __shared__ unsigned short Vt[2][128 * LDV];   // V tile transposed [d][kv]

  const int tid = threadIdx.x;
  const int l   = tid & 63;
  const int w   = tid >> 6;     // wave 0..7
  const int ql  = l & 15;
  const int hi  = l >> 4;

  // XCD-chunked bijective swizzle (256 blocks, 8 XCDs, 32 per XCD)
  const int idx = blockIdx.x;
  const int swz = (idx & 7) * 32 + (idx >> 3);
  const int b   = swz >> 4;     // batch 0..15
  const int qt  = swz & 15;     // q-tile (128 rows) 0..15
  const int q0  = qt * 128 + w * 16;

  const float* Qb = Q + ((size_t)b * Ss + q0) * Dd;
  const float* Kb = K + (size_t)b * Ss * Dd;
  const float* Vb = V + (size_t)b * Ss * Dd;
  float*       Ob = O + ((size_t)b * Ss + q0) * Dd;

  // Q fragments (B-operand of swapped QK^T): qf[dq][j] = Q[q0+ql][dq*32+hi*8+j]
  s16x8 qf[4];
  #pragma unroll
  for (int dq = 0; dq < 4; ++dq) {
    f32x4 fa = *(const f32x4*)(Qb + ql * Dd + dq * 32 + hi * 8);
    f32x4 fb = *(const f32x4*)(Qb + ql * Dd + dq * 32 + hi * 8 + 4);
    union { s16x8 v; s16x4 h[2]; } u;
    u.h[0] = cvt4(fa); u.h[1] = cvt4(fb);
    qf[dq] = u.v;
  }

  const f32x4 vzero = {0.f, 0.f, 0.f, 0.f};
  f32x4 acc[8];
  #pragma unroll
  for (int i = 0; i < 8; ++i) acc[i] = vzero;
  float m2   = -__builtin_inff();
  float lsum = 0.f;
  constexpr float Cs  = 1.44269504088896340736f / 11.31370849898476039041f; // log2e/sqrt(128)
  constexpr float THR = 10.0f;

  const int dV  = tid & 127;     // V staging column (d)
  const int gV  = tid >> 7;      // 0..3

  f32x4 kreg[4];
  f32x4 vreg[4];

  auto load_tile = [&](int t) {
    const float* Kp = Kb + (size_t)t * 64 * Dd;
    #pragma unroll
    for (int i = 0; i < 4; ++i) {
      int u = i * 512 + tid;
      kreg[i] = *(const f32x4*)(Kp + (size_t)(u >> 5) * Dd + (u & 31) * 4);
    }
    const float* Vp = Vb + (size_t)t * 64 * Dd + dV;
    #pragma unroll
    for (int i = 0; i < 4; ++i) {
      int a = i * 4 + gV;
      const float* vp = Vp + (size_t)(a * 4) * Dd;
      f32x4 tt; tt[0] = vp[0]; tt[1] = vp[Dd]; tt[2] = vp[2 * Dd]; tt[3] = vp[3 * Dd];
      vreg[i] = tt;
    }
  };
  auto write_tile = [&](int c) {
    #pragma unroll
    for (int i = 0; i < 4; ++i) {
      int u = i * 512 + tid;
      *(s16x4*)&Kt[c][(u >> 5) * LDK + (u & 31) * 4] = cvt4(kreg[i]);
    }
    #pragma unroll
    for (int i = 0; i < 4; ++i) {
      int a = i * 4 + gV;
      *(s16x4*)&Vt[c][dV * LDV + a * 4] = cvt4(vreg[i]);
    }
  };

  // ---- prologue ----
  load_tile(0);
  write_tile(0);
  load_tile(1);
  __syncthreads();

  for (int t = 0; t < NT; ++t) {
    const int c = t & 1;

    // ---- S^T = K · Q^T (16x16x32) ----
    f32x4 p4[4];
    __builtin_amdgcn_s_setprio(1);
    #pragma unroll
    for (int kk = 0; kk < 4; ++kk) {
      f32x4 s = vzero;
      #pragma unroll
      for (int dq = 0; dq < 4; ++dq) {
        s16x8 afr = *(const s16x8*)&Kt[c][(kk * 16 + ql) * LDK + dq * 32 + hi * 8];
        s = __builtin_amdgcn_mfma_f32_16x16x32_bf16(afr, qf[dq], s, 0, 0, 0);
      }
      p4[kk] = s;
    }
    __builtin_amdgcn_s_setprio(0);

    // ---- online softmax (lane-local q row) with defer-max ----
    float tmax = p4[0][0];
    #pragma unroll
    for (int kk = 0; kk < 4; ++kk)
      #pragma unroll
      for (int r = 0; r < 4; ++r) tmax = fmaxf(tmax, p4[kk][r]);
    tmax = fmaxf(tmax, __shfl_xor(tmax, 16));
    tmax = fmaxf(tmax, __shfl_xor(tmax, 32));
    float mt = tmax * Cs;
    if (__any(mt > m2 + THR)) {
      float m2n   = fmaxf(m2, mt);
      float alpha = __builtin_amdgcn_exp2f(m2 - m2n);
      f32x4 av;
      #pragma unroll
      for (int r = 0; r < 4; ++r) av[r] = __shfl(alpha, hi * 4 + r);
      #pragma unroll
      for (int dt = 0; dt < 8; ++dt) acc[dt] *= av;
      lsum *= alpha;
      m2 = m2n;
    }
    float rsum = 0.f;
    #pragma unroll
    for (int kk = 0; kk < 4; ++kk)
      #pragma unroll
      for (int r = 0; r < 4; ++r) {
        float e = __builtin_amdgcn_exp2f(fmaf(p4[kk][r], Cs, -m2));
        p4[kk][r] = e;
        rsum += e;
      }
    rsum += __shfl_xor(rsum, 16);
    rsum += __shfl_xor(rsum, 32);
    lsum += rsum;

    // ---- overlap: write staged tile t+1 -> buf^1; issue loads for t+2 ----
    if (t + 1 < NT) write_tile(c ^ 1);
    if (t + 2 < NT) load_tile(t + 2);

    // P -> bf16 fragments; S^T C-row (4hi+r) is the PV A k-index
    s16x4 pa[4];
    #pragma unroll
    for (int kk = 0; kk < 4; ++kk) pa[kk] = cvt4(p4[kk]);

    // ---- O += P · V (16x16x32; B-frag = two b64 reads, k-order matches A concat) ----
    __builtin_amdgcn_s_setprio(1);
    #pragma unroll
    for (int pvb = 0; pvb < 2; ++pvb) {
      union { s16x8 v; s16x4 h[2]; } ua;
      ua.h[0] = pa[pvb * 2]; ua.h[1] = pa[pvb * 2 + 1];
      #pragma unroll
      for (int dt = 0; dt < 8; ++dt) {
        const unsigned short* vrow = &Vt[c][(dt * 16 + ql) * LDV];
        union { s16x8 v; s16x4 h[2]; } ub;
        ub.h[0] = *(const s16x4*)&vrow[pvb * 32 + hi * 4];
        ub.h[1] = *(const s16x4*)&vrow[pvb * 32 + 16 + hi * 4];
        acc[dt] = __builtin_amdgcn_mfma_f32_16x16x32_bf16(ua.v, ub.v, acc[dt], 0, 0, 0);
      }
    }
    __builtin_amdgcn_s_setprio(0);

    __syncthreads();
  }

  // ---- epilogue ----
  float inv[4];
  #pragma unroll
  for (int r = 0; r < 4; ++r) inv[r] = 1.f / __shfl(lsum, hi * 4 + r);
  #pragma unroll
  for (int dt = 0; dt < 8; ++dt) {
    #pragma unroll
    for (int r = 0; r < 4; ++r) {
      Ob[(size_t)(hi * 4 + r) * Dd + dt * 16 + ql] = acc[dt][r] * inv[r];
    }
  }
}

extern "C" void kernel_launch(void* const* d_in, const int* in_sizes, int n_in,
                              void* d_out, int out_size, void* d_ws, size_t ws_size,
                              hipStream_t stream) {
  const float* Q = (const float*)d_in[0];
  const float* K = (const float*)d_in[1];
  const float* V = (const float*)d_in[2];
  float* O = (float*)d_out;
  attn_kernel<<<dim3(Bb * (Ss / 128)), dim3(512), 0, stream>>>(Q, K, V, O);
}